// Round 1
// 889.757 us; speedup vs baseline: 1.0450x; 1.0450x over previous
//
#include <hip/hip_runtime.h>

#define T_STEPS 1460
#define G_CELLS 5000
#define NPARAM 20
#define UH_L 15
#define NZ 1e-5f
#define KT 32                       // fir time-chunk: read-amp (KT+14)/KT = 1.44
#define DCH 10                      // rec chunk depth (T_STEPS % DCH == 0)
#define NCH (T_STEPS / DCH)         // 146 chunks

__device__ __forceinline__ float sigmoidf(float x) {
    return 1.0f / (1.0f + __expf(-x));
}

// fast pow for x>0: x^y = exp2(y*log2(x)) using raw gfx950 transcendentals
__device__ __forceinline__ float fast_pow(float x, float y) {
    return __builtin_amdgcn_exp2f(y * __builtin_amdgcn_logf(x));
}

// ---------------- gamma unit-hydrograph weights, stored [l][G] ----------------
__global__ void uh_kernel(const float* __restrict__ params,
                          float* __restrict__ uh1T, float* __restrict__ uh2T) {
    int g = blockIdx.x * blockDim.x + threadIdx.x;
    if (g >= G_CELLS) return;
    const float* pr = params + ((size_t)(T_STEPS - 1) * G_CELLS + g) * NPARAM;
    float a1 = 0.3f  + sigmoidf(pr[16]) * (20.0f - 0.3f);
    float b1 = 0.01f + sigmoidf(pr[17]) * (5.0f  - 0.01f);
    float a2 = 0.5f  + sigmoidf(pr[18]) * (13.0f - 0.5f);
    float b2 = 0.15f + sigmoidf(pr[19]) * (1.5f  - 0.15f);
    float w1[UH_L], w2[UH_L];
    float s1 = 0.f, s2 = 0.f;
    #pragma unroll
    for (int l = 0; l < UH_L; ++l) {
        float t = (float)l + 0.5f;
        w1[l] = fast_pow(t, a1 - 1.0f) * __expf(-t / b1);
        w2[l] = fast_pow(t, a2 - 1.0f) * __expf(-t / b2);
        s1 += w1[l]; s2 += w2[l];
    }
    float r1 = 1.0f / s1, r2 = 1.0f / s2;
    #pragma unroll
    for (int l = 0; l < UH_L; ++l) {
        uh1T[l * G_CELLS + g] = w1[l] * r1;
        uh2T[l * G_CELLS + g] = w2[l] * r2;
    }
}

// ---------------- sequential state recurrence ---------------------------------
// Two-wave producer/consumer split per 64-cell block:
//   wave 0: snow/soil chain (S, W, C) -> wa            [never reads V, P]
//   wave 1: vadose/phreatic chain (V, P) + all stores   [consumes wa, PET only]
// wa handed through a double-buffered LDS ring, one barrier per DCH-step chunk.
// The two serial dependency chains run concurrently on different SIMDs,
// halving the per-wave serial instruction stream. Arithmetic is bit-identical
// to the single-wave version (same ops, same order).
__global__ void __launch_bounds__(128, 1) rec_kernel(
        const float* __restrict__ x_phy, const float* __restrict__ params,
        float2* __restrict__ q2, float* __restrict__ qgw) {
    const int lane = threadIdx.x & 63;
    const int wid  = threadIdx.x >> 6;
    const int g    = blockIdx.x * 64 + lane;
    const int gc   = (g < G_CELLS) ? g : (G_CELLS - 1);   // clamp: no early return (barriers)
    const bool valid = (g < G_CELLS);

    __shared__ float s_wa[2][DCH][64];   // 5 KB, stride-4B per lane (conflict-free)

    const float* pr = params + ((size_t)(T_STEPS - 1) * G_CELLS + gc) * NPARAM;
    const int STR = G_CELLS * 3;

    // ---- wave-0 state & params (snow/soil) ----
    const float ddf_min    = sigmoidf(pr[0]) * 20.f;
    const float ddf_plus   = sigmoidf(pr[1]) * 20.f;
    const float Tbm        = -2.f + sigmoidf(pr[2]) * 5.f;
    const float Kcum       = 0.01f + sigmoidf(pr[3]) * 0.19f;
    const float fcmin      = sigmoidf(pr[4]) * 0.1f;
    const float fcmin_plus = 0.01f + sigmoidf(pr[5]) * 0.24f;
    const float Ccum       = 0.005f + sigmoidf(pr[6]) * 0.045f;
    const float Tbf        = -5.f + sigmoidf(pr[7]) * 7.f;
    const float Kf         = sigmoidf(pr[8]) * 5.f;
    const float exp_fe     = sigmoidf(pr[9]);
    const float ddf_sum = ddf_min + ddf_plus;
    const float dmK     = ddf_min * Kcum;
    const float fc_sum  = fcmin + fcmin_plus;
    const float fcC     = fc_sum * Ccum;
    float S = NZ, W = NZ, C = NZ;

    // ---- wave-1 state & params (vadose/phreatic + routing outputs) ----
    const float ET_eff = sigmoidf(pr[10]) * 3.f;
    const float cr     = sigmoidf(pr[11]);
    const float cvp    = 1e-5f + sigmoidf(pr[12]) * (0.02f - 1e-5f);
    const float cv     = sigmoidf(pr[13]) * 0.1f;
    const float cp     = 1e-5f + sigmoidf(pr[14]) * (0.01f - 1e-5f);
    const float Vmax   = 0.001f + sigmoidf(pr[15]) * (500.f - 0.001f);
    const float invVmax = 1.0f / Vmax;
    float V = 0.5f * Vmax, P = NZ;

    const float* base  = x_phy + (size_t)gc * 3;       // Pp at +0, Tt at +1
    const float* baseE = x_phy + (size_t)gc * 3 + 2;   // PET

    float A[DCH][2], B[DCH][2];   // wave-0 double-buffered (Pp, Tt)
    float PA[DCH], PB[DCH];       // wave-1 double-buffered PET

    auto LOADPT = [&](float (&buf)[DCH][2], int c) {
        const float* pp = base + (size_t)c * DCH * STR;
        #pragma unroll
        for (int j = 0; j < DCH; ++j) { buf[j][0] = pp[0]; buf[j][1] = pp[1]; pp += STR; }
    };
    auto LOADPE = [&](float (&buf)[DCH], int c) {
        const float* pp = baseE + (size_t)c * DCH * STR;
        #pragma unroll
        for (int j = 0; j < DCH; ++j) { buf[j] = *pp; pp += STR; }
    };

    auto SNOW = [&](float (&buf)[DCH][2], int c) {
        #pragma unroll
        for (int j = 0; j < DCH; ++j) {
            float Pp = buf[j][0], Tt = buf[j][1];
            float rain = (Tt >= 0.f) ? Pp : 0.f;
            float snow = Pp - rain;
            float xb   = fmaxf(Tbf - Tt, NZ);
            float pot_fr = Kf * fast_pow(xb, exp_fe);
            float fr   = fminf(pot_fr, W);
            W -= fr; S += fr;
            float ddf  = fminf(ddf_sum, fmaf(dmK, C, ddf_min));
            float Ssn  = S + snow;
            float melt = fminf(fmaxf(ddf * (Tt - Tbm), 0.f), Ssn);
            S = Ssn - melt;
            C = (S > NZ) ? (C + melt) : 0.f;
            float wrf  = fmaxf(fmaf(-fcC, C, fc_sum), fcmin);
            float wr   = wrf * S;
            float wtmp = W + melt + rain;
            float wa   = fmaxf(wtmp - wr, 0.f);
            W = (wa > 0.f) ? wr : wtmp;
            s_wa[c & 1][j][lane] = wa;
        }
    };

    auto VP = [&](float (&pe)[DCH], int c) {
        size_t t0 = (size_t)c * DCH;
        #pragma unroll
        for (int j = 0; j < DCH; ++j) {
            float wa   = s_wa[c & 1][j][lane];
            float RET  = ET_eff * pe[j];
            float ratio = V * invVmax;
            float crr   = cr * ratio;
            float ht0   = crr * wa;
            float infil = fmaxf(wa - ht0 - RET, 0.f);
            float ht1   = crr * ratio * infil;
            float ht2   = cv * V;
            float v2p   = cvp * V;
            V = V + infil - ht1 - ht2 - v2p;
            float over  = fmaxf(V - Vmax, 0.f);
            V -= over; ht1 += over;
            P += v2p;
            float ht3 = cp * P;
            P -= ht3;
            if (valid) {
                q2 [(t0 + j) * G_CELLS + g] = make_float2(ht0, ht1);
                qgw[(t0 + j) * G_CELLS + g] = ht2 + ht3;
            }
        }
    };

    // ---- software pipeline: wave0 produces chunk c+1 while wave1 consumes c ----
    if (wid == 0) {
        LOADPT(A, 0); LOADPT(B, 1);   // chunk k lives in (k&1)?B:A
        SNOW(A, 0);
    } else {
        LOADPE(PA, 0); LOADPE(PB, 1); // chunk k lives in (k&1)?PB:PA
    }
    __syncthreads();                  // s_wa[0] (chunk 0) ready

    for (int c = 0; c < NCH; ++c) {
        if (wid == 0) {
            if (c + 2 < NCH) LOADPT((c & 1) ? B : A, c + 2);  // refill freed buffer
            if (c + 1 < NCH) SNOW(((c + 1) & 1) ? B : A, c + 1);
        } else {
            VP((c & 1) ? PB : PA, c);
            if (c + 2 < NCH) LOADPE((c & 1) ? PB : PA, c + 2);
        }
        __syncthreads();              // publish s_wa[(c+1)&1]; retire s_wa[c&1]
    }
}

// ---------------- FIR (15-tap causal) + groundwater combine -------------------
// Mod-15 ring with compile-time indices: no register shifting, no spill.
__global__ void __launch_bounds__(256) fir_kernel(
        const float2* __restrict__ q2, const float* __restrict__ qgw,
        const float* __restrict__ uh1T, const float* __restrict__ uh2T,
        float* __restrict__ out) {
    int g = blockIdx.x * 256 + threadIdx.x;
    if (g >= G_CELLS) return;
    int t0 = blockIdx.y * KT;

    float w1[UH_L], w2[UH_L];
    #pragma unroll
    for (int l = 0; l < UH_L; ++l) {
        w1[l] = uh1T[l * G_CELLS + g];
        w2[l] = uh2T[l * G_CELLS + g];
    }
    // ring slot for time tau = (tau - t0 + 14) mod 15 — compile-time after unroll
    float r0[UH_L], r1[UH_L];
    #pragma unroll
    for (int k = 0; k < UH_L - 1; ++k) {      // preload tau = t0-14+k  -> slot k
        int tq = t0 - (UH_L - 1) + k;
        if (tq >= 0) {
            float2 v = q2[(size_t)tq * G_CELLS + g];
            r0[k] = v.x; r1[k] = v.y;
        } else { r0[k] = 0.f; r1[k] = 0.f; }
    }
    #pragma unroll
    for (int j = 0; j < KT; ++j) {
        int t = t0 + j;
        if (t < T_STEPS) {                    // uniform within block
            const int ns = (j + UH_L - 1) % UH_L;   // slot for the new sample
            float2 v = q2[(size_t)t * G_CELLS + g];
            r0[ns] = v.x; r1[ns] = v.y;
            float acc = qgw[(size_t)t * G_CELLS + g];
            #pragma unroll
            for (int l = 0; l < UH_L; ++l) {
                const int idx = (j - l + UH_L - 1) % UH_L;   // slot of tau = t-l
                acc += r0[idx] * w1[l] + r1[idx] * w2[l];
            }
            out[(size_t)t * G_CELLS + g] = acc;
        }
    }
}

extern "C" void kernel_launch(void* const* d_in, const int* in_sizes, int n_in,
                              void* d_out, int out_size, void* d_ws, size_t ws_size,
                              hipStream_t stream) {
    const float* x_phy  = (const float*)d_in[0];   // (T, G, 3) f32
    const float* params = (const float*)d_in[1];   // (T, G, 20) f32
    float* out = (float*)d_out;                    // (T, G) f32

    char* ws = (char*)d_ws;
    float2* q2   = (float2*)ws;                                        // T*G*8 B
    float*  qgw  = (float*)(ws + (size_t)T_STEPS * G_CELLS * 8);       // T*G*4 B
    float*  uh1T = (float*)(ws + (size_t)T_STEPS * G_CELLS * 12);      // 15*G*4 B
    float*  uh2T = uh1T + UH_L * G_CELLS;                              // 15*G*4 B

    uh_kernel<<<(G_CELLS + 255) / 256, 256, 0, stream>>>(params, uh1T, uh2T);
    rec_kernel<<<(G_CELLS + 63) / 64, 128, 0, stream>>>(x_phy, params, q2, qgw);
    dim3 fgrid((G_CELLS + 255) / 256, (T_STEPS + KT - 1) / KT);
    fir_kernel<<<fgrid, 256, 0, stream>>>(q2, qgw, uh1T, uh2T, out);
}

// Round 4
// 874.201 us; speedup vs baseline: 1.0635x; 1.0178x over previous
//
#include <hip/hip_runtime.h>

#define T_STEPS 1460
#define G_CELLS 5000
#define NPARAM 20
#define UH_L 15
#define NZ 1e-5f
#define DCH 10                      // chunk depth (T_STEPS % DCH == 0)
#define NCH (T_STEPS / DCH)         // 146 chunks

__device__ __forceinline__ float sigmoidf(float x) {
    return 1.0f / (1.0f + __expf(-x));
}

// fast pow for x>0: x^y = exp2(y*log2(x)) using raw gfx950 transcendentals
__device__ __forceinline__ float fast_pow(float x, float y) {
    return __builtin_amdgcn_exp2f(y * __builtin_amdgcn_logf(x));
}

// ------------------------------------------------------------------------------
// Fully fused HMETS: 3-wave pipeline per 64-cell block.
//   w0: snow/soil chain (S,W,C) -> wa                      [LDS s_wa]
//   w1: vadose/phreatic (V,P) -> ht0,ht1,gw + FIR taps 0-2 [LDS s_ht, s_p]
//   w2: FIR taps 3-14 + store out
// Removes the q2/qgw global round-trip (88 MB write + 117 MB re-read) and the
// separate fir/uh kernels: the recurrence emits ht-values in time order, which
// is exactly what the causal 15-tap FIR consumes. Arithmetic keeps the same
// source expression forms as the last passing kernel (same fma contraction;
// FIR accumulation split at a tap boundary preserves the exact add order).
// Ring slots are compile-time: chunk offset (10*c mod 15) in {0,10,5} via c%3,
// passed as a literal through the FIRR macro.
// ------------------------------------------------------------------------------
__global__ void __launch_bounds__(192, 1) fused_kernel(
        const float* __restrict__ x_phy, const float* __restrict__ params,
        float* __restrict__ out) {
    const int lane = threadIdx.x & 63;
    const int wid  = threadIdx.x >> 6;
    const int g    = blockIdx.x * 64 + lane;
    const int gc   = (g < G_CELLS) ? g : (G_CELLS - 1);   // clamp: no early return (barriers)
    const bool valid = (g < G_CELLS);

    __shared__ float  s_wa[2][DCH][64];   // w0 -> w1   (5 KB)
    __shared__ float2 s_ht[2][DCH][64];   // w1 -> w2   (10 KB, 8B/lane: free 2-way alias)
    __shared__ float  s_p [2][DCH][64];   // w1 -> w2   (5 KB)

    const float* pr = params + ((size_t)(T_STEPS - 1) * G_CELLS + gc) * NPARAM;
    const int STR = G_CELLS * 3;

    const float* base  = x_phy + (size_t)gc * 3;   // Pp at +0, Tt at +1
    const float* baseE = base + 2;                 // PET

    // ---- wave-0 state (snow/soil) ----
    float A[DCH][2], B[DCH][2], Cb[DCH][2];        // triple-buffered (Pp,Tt)
    float S = NZ, W = NZ, C = NZ;
    float ddf_min = 0.f, Tbm = 0.f, fcmin = 0.f, Tbf = 0.f, Kf = 0.f, exp_fe = 0.f;
    float ddf_sum = 0.f, dmK = 0.f, fc_sum = 0.f, fcC = 0.f;

    // ---- wave-1 state (vadose/phreatic + FIR taps 0..2) ----
    float PA[DCH], PB[DCH], PC[DCH];               // triple-buffered PET
    float ET_eff = 0.f, cr = 0.f, cvp = 0.f, cv = 0.f, cp = 0.f;
    float Vmax = 0.f, invVmax = 0.f, V = 0.f, P = NZ;
    float a1p = 0.f, a2p = 0.f, b1p = 0.f, b2p = 0.f;  // ht0/ht1 history (t-1, t-2)

    // ---- FIR weights (waves 1 & 2) ----
    float W1t[UH_L], W2t[UH_L];

    // ---- wave-2 state (FIR rings) ----
    float r0[UH_L], r1[UH_L];

    auto LOADPT = [&](float (&buf)[DCH][2], int c) {
        const float* pp = base + (size_t)c * DCH * STR;
        #pragma unroll
        for (int j = 0; j < DCH; ++j) { buf[j][0] = pp[0]; buf[j][1] = pp[1]; pp += STR; }
    };
    auto LOADPE = [&](float (&buf)[DCH], int c) {
        const float* pp = baseE + (size_t)c * DCH * STR;
        #pragma unroll
        for (int j = 0; j < DCH; ++j) { buf[j] = *pp; pp += STR; }
    };

    // ---------------- per-wave prologue (no barriers) ----------------
    if (wid == 0) {
        ddf_min          = sigmoidf(pr[0]) * 20.f;
        float ddf_plus   = sigmoidf(pr[1]) * 20.f;
        Tbm              = -2.f + sigmoidf(pr[2]) * 5.f;
        float Kcum       = 0.01f + sigmoidf(pr[3]) * 0.19f;
        fcmin            = sigmoidf(pr[4]) * 0.1f;
        float fcmin_plus = 0.01f + sigmoidf(pr[5]) * 0.24f;
        float Ccum       = 0.005f + sigmoidf(pr[6]) * 0.045f;
        Tbf              = -5.f + sigmoidf(pr[7]) * 7.f;
        Kf               = sigmoidf(pr[8]) * 5.f;
        exp_fe           = sigmoidf(pr[9]);
        ddf_sum = ddf_min + ddf_plus;
        dmK     = ddf_min * Kcum;
        fc_sum  = fcmin + fcmin_plus;
        fcC     = fc_sum * Ccum;
        LOADPT(A, 0); LOADPT(B, 1); LOADPT(Cb, 2);
    } else {
        // FIR weights — identical math to the old uh_kernel (bit-identical)
        float a1 = 0.3f  + sigmoidf(pr[16]) * (20.0f - 0.3f);
        float b1 = 0.01f + sigmoidf(pr[17]) * (5.0f  - 0.01f);
        float a2 = 0.5f  + sigmoidf(pr[18]) * (13.0f - 0.5f);
        float b2 = 0.15f + sigmoidf(pr[19]) * (1.5f  - 0.15f);
        float s1 = 0.f, s2 = 0.f;
        #pragma unroll
        for (int l = 0; l < UH_L; ++l) {
            float t = (float)l + 0.5f;
            W1t[l] = fast_pow(t, a1 - 1.0f) * __expf(-t / b1);
            W2t[l] = fast_pow(t, a2 - 1.0f) * __expf(-t / b2);
            s1 += W1t[l]; s2 += W2t[l];
        }
        float rs1 = 1.0f / s1, rs2 = 1.0f / s2;
        #pragma unroll
        for (int l = 0; l < UH_L; ++l) { W1t[l] *= rs1; W2t[l] *= rs2; }

        if (wid == 1) {
            ET_eff = sigmoidf(pr[10]) * 3.f;
            cr     = sigmoidf(pr[11]);
            cvp    = 1e-5f + sigmoidf(pr[12]) * (0.02f - 1e-5f);
            cv     = sigmoidf(pr[13]) * 0.1f;
            cp     = 1e-5f + sigmoidf(pr[14]) * (0.01f - 1e-5f);
            Vmax   = 0.001f + sigmoidf(pr[15]) * (500.f - 0.001f);
            invVmax = 1.0f / Vmax;
            V = 0.5f * Vmax;
            LOADPE(PA, 0); LOADPE(PB, 1); LOADPE(PC, 2);
        } else {
            #pragma unroll
            for (int l = 0; l < UH_L; ++l) { r0[l] = 0.f; r1[l] = 0.f; }  // t<0 -> 0 pad
        }
    }

    auto SNOW = [&](float (&buf)[DCH][2], int c) {
        #pragma unroll
        for (int j = 0; j < DCH; ++j) {
            float Pp = buf[j][0], Tt = buf[j][1];
            float rain = (Tt >= 0.f) ? Pp : 0.f;
            float snow = Pp - rain;
            float xb   = fmaxf(Tbf - Tt, NZ);
            float pot_fr = Kf * fast_pow(xb, exp_fe);
            float fr   = fminf(pot_fr, W);
            W -= fr; S += fr;
            float ddf  = fminf(ddf_sum, fmaf(dmK, C, ddf_min));
            float Ssn  = S + snow;
            float melt = fminf(fmaxf(ddf * (Tt - Tbm), 0.f), Ssn);
            S = Ssn - melt;
            C = (S > NZ) ? (C + melt) : 0.f;
            float wrf  = fmaxf(fmaf(-fcC, C, fc_sum), fcmin);
            float wr   = wrf * S;
            float wtmp = W + melt + rain;
            float wa   = fmaxf(wtmp - wr, 0.f);
            W = (wa > 0.f) ? wr : wtmp;
            s_wa[c & 1][j][lane] = wa;
        }
    };

    auto VPP = [&](float (&pe)[DCH], int c) {
        #pragma unroll
        for (int j = 0; j < DCH; ++j) {
            float wa   = s_wa[c & 1][j][lane];
            float RET  = ET_eff * pe[j];
            float ratio = V * invVmax;
            float crr   = cr * ratio;
            float ht0   = crr * wa;
            float infil = fmaxf(wa - ht0 - RET, 0.f);
            float ht1   = crr * ratio * infil;
            float ht2   = cv * V;
            float v2p   = cvp * V;
            V = V + infil - ht1 - ht2 - v2p;
            float over  = fmaxf(V - Vmax, 0.f);
            V -= over; ht1 += over;
            P += v2p;
            float ht3 = cp * P;
            P -= ht3;
            float gw = ht2 + ht3;                       // == old qgw value
            s_ht[c & 1][j][lane] = make_float2(ht0, ht1);
            // FIR taps 0..2, exact same expression form / order as before
            float p = gw;
            p += ht0 * W1t[0] + ht1 * W2t[0];
            p += a1p * W1t[1] + b1p * W2t[1];
            p += a2p * W1t[2] + b2p * W2t[2];
            s_p[c & 1][j][lane] = p;
            a2p = a1p; a1p = ht0;
            b2p = b1p; b1p = ht1;
        }
    };

    // FIR taps 3..14; OFF must be a literal ((10*c) mod 15): 0, 10 or 5.
    // All ring indices are compile-time after unroll.
    #define FIRR(OFF, cc)                                                      \
    do {                                                                       \
        const int c_ = (cc);                                                   \
        size_t t0 = (size_t)c_ * DCH;                                          \
        _Pragma("unroll")                                                      \
        for (int j = 0; j < DCH; ++j) {                                        \
            float2 h  = s_ht[c_ & 1][j][lane];                                 \
            float acc = s_p [c_ & 1][j][lane];                                 \
            r0[((OFF) + j) % UH_L] = h.x;                                      \
            r1[((OFF) + j) % UH_L] = h.y;                                      \
            _Pragma("unroll")                                                  \
            for (int l = 3; l < UH_L; ++l) {                                   \
                const int idx = ((OFF) + j - l + 2 * UH_L) % UH_L;             \
                acc += r0[idx] * W1t[l] + r1[idx] * W2t[l];                    \
            }                                                                  \
            if (valid) out[(t0 + j) * G_CELLS + g] = acc;                      \
        }                                                                      \
    } while (0)

    // ---------------- pipeline: tick tau runs stage i on chunk tau-i ----------
    for (int tau = 0; tau < NCH + 2; ++tau) {
        if (wid == 0) {
            if (tau < NCH) {
                int c = tau;
                switch (c % 3) {
                case 0:  SNOW(A, c);  if (c + 3 < NCH) LOADPT(A, c + 3);  break;
                case 1:  SNOW(B, c);  if (c + 3 < NCH) LOADPT(B, c + 3);  break;
                default: SNOW(Cb, c); if (c + 3 < NCH) LOADPT(Cb, c + 3); break;
                }
            }
        } else if (wid == 1) {
            int c = tau - 1;
            if (c >= 0 && c < NCH) {
                switch (c % 3) {
                case 0:  VPP(PA, c); if (c + 3 < NCH) LOADPE(PA, c + 3); break;
                case 1:  VPP(PB, c); if (c + 3 < NCH) LOADPE(PB, c + 3); break;
                default: VPP(PC, c); if (c + 3 < NCH) LOADPE(PC, c + 3); break;
                }
            }
        } else {
            int c = tau - 2;
            if (c >= 0) {
                switch (c % 3) {
                case 0:  FIRR(0,  c); break;
                case 1:  FIRR(10, c); break;
                default: FIRR(5,  c); break;
                }
            }
        }
        __syncthreads();   // single barrier per tick, reached by all 3 waves
    }
    #undef FIRR
}

extern "C" void kernel_launch(void* const* d_in, const int* in_sizes, int n_in,
                              void* d_out, int out_size, void* d_ws, size_t ws_size,
                              hipStream_t stream) {
    const float* x_phy  = (const float*)d_in[0];   // (T, G, 3) f32
    const float* params = (const float*)d_in[1];   // (T, G, 20) f32
    float* out = (float*)d_out;                    // (T, G) f32
    (void)d_ws; (void)ws_size; (void)in_sizes; (void)n_in; (void)out_size;

    fused_kernel<<<(G_CELLS + 63) / 64, 192, 0, stream>>>(x_phy, params, out);
}